// Round 13
// baseline (230.680 us; speedup 1.0000x reference)
//
#include <hip/hip_runtime.h>

typedef unsigned short u16;
typedef unsigned int   u32;
typedef unsigned long long u64;
typedef __bf16 bf16x8 __attribute__((ext_vector_type(8)));
typedef float  f32x4  __attribute__((ext_vector_type(4)));

#define B_  16
#define S_  1024
#define L_  512
#define D_  1024
#define H_  8
#define WD_ 256
#define KP_ (D_ + WD_)

__device__ __forceinline__ u16 f2bf(float f) {
    u32 u = __float_as_uint(f);
    return (u16)((u + 0x7FFFu + ((u >> 16) & 1u)) >> 16);
}
__device__ __forceinline__ float bf2f(u16 h) {
    return __uint_as_float(((u32)h) << 16);
}
__device__ __forceinline__ void gload16(const void* g, void* l) {
    __builtin_amdgcn_global_load_lds(
        (const __attribute__((address_space(1))) u32*)(unsigned long long)(g),
        (__attribute__((address_space(3))) u32*)(unsigned long long)(l),
        16, 0, 0);
}

// ---------- single fused prep kernel ----------
__global__ __launch_bounds__(256) void prep_k(
    const float* __restrict__ enc,
    const float* __restrict__ wk, const float* __restrict__ wv,
    const float* __restrict__ wq, const float* __restrict__ te,
    const float* __restrict__ bk, const float* __restrict__ bv,
    const float* __restrict__ bq,
    const float* __restrict__ wo, const float* __restrict__ wproj,
    const float* __restrict__ bo, const float* __restrict__ bproj,
    u16* __restrict__ enc_bf, u16* __restrict__ wkvq, u16* __restrict__ te_bf,
    float* __restrict__ bkvq, u16* __restrict__ wot,
    u16* __restrict__ wp1, u16* __restrict__ wfin,
    float* __restrict__ beff, float qs)
{
    __shared__ float tile[64][65];
    const int bid = blockIdx.x;
    if (bid < 16384) {
        const int i = (bid * 256 + threadIdx.x) * 4;
        const float4 v = *(const float4*)(enc + i);
        ushort4 o;
        o.x = f2bf(v.x); o.y = f2bf(v.y); o.z = f2bf(v.z); o.w = f2bf(v.w);
        *(ushort4*)(enc_bf + i) = o;
    } else if (bid < 19456) {
        const int b2 = bid - 16384;
        const int plane = b2 >> 10;
        const int i = ((b2 & 1023) * 256 + threadIdx.x) * 4;
        const float* src = plane == 0 ? wk : (plane == 1 ? wv : wq);
        const float s = plane == 2 ? qs : 1.0f;
        const float4 v = *(const float4*)(src + i);
        ushort4 o;
        o.x = f2bf(v.x * s); o.y = f2bf(v.y * s); o.z = f2bf(v.z * s); o.w = f2bf(v.w * s);
        *(ushort4*)(wkvq + (size_t)plane * 1048576 + i) = o;
    } else if (bid < 19706) {
        const int i = ((bid - 19456) * 256 + threadIdx.x) * 4;
        if (i < 256000) {
            const float4 v = *(const float4*)(te + i);
            ushort4 o;
            o.x = f2bf(v.x); o.y = f2bf(v.y); o.z = f2bf(v.z); o.w = f2bf(v.w);
            *(ushort4*)(te_bf + i) = o;
        }
    } else if (bid < 19709) {
        const int i = (bid - 19706) * 1024 + threadIdx.x * 4;
        #pragma unroll
        for (int j = 0; j < 4; ++j) {
            const int idx = i + j;
            bkvq[idx] = (idx < 1024) ? bk[idx]
                      : (idx < 2048 ? bv[idx - 1024] : bq[idx - 2048] * qs);
        }
    } else if (bid < 19965) {
        const int cid = bid - 19709;
        const int t0 = (cid & 15) * 64;
        const int k0 = (cid >> 4) * 64;
        const int tr = threadIdx.x >> 4;
        const int tc = threadIdx.x & 15;
        #pragma unroll
        for (int i = 0; i < 4; ++i) {
            const int r = tr + i * 16;
            const float4 v = *(const float4*)(wo + (size_t)(t0 + r) * 1024 + k0 + tc * 4);
            tile[r][tc * 4 + 0] = v.x; tile[r][tc * 4 + 1] = v.y;
            tile[r][tc * 4 + 2] = v.z; tile[r][tc * 4 + 3] = v.w;
        }
        __syncthreads();
        #pragma unroll
        for (int i = 0; i < 4; ++i) {
            const int r = tr + i * 16;
            ushort4 o;
            o.x = f2bf(tile[tc * 4 + 0][r]);
            o.y = f2bf(tile[tc * 4 + 1][r]);
            o.z = f2bf(tile[tc * 4 + 2][r]);
            o.w = f2bf(tile[tc * 4 + 3][r]);
            *(ushort4*)(wot + (size_t)(k0 + r) * 1024 + t0 + tc * 4) = o;
        }
    } else if (bid < 21245) {
        const int i = ((bid - 19965) * 256 + threadIdx.x) * 4;
        const int n = i / 1280, c = i % 1280;
        const float4 v = *(const float4*)(wproj + i);
        ushort4 o;
        o.x = f2bf(v.x); o.y = f2bf(v.y); o.z = f2bf(v.z); o.w = f2bf(v.w);
        if (c < 1024) *(ushort4*)(wp1 + (size_t)n * 1024 + c) = o;
        else          *(ushort4*)(wfin + (size_t)n * 1280 + c) = o;
    } else {
        const int w = threadIdx.x >> 6, lane = threadIdx.x & 63;
        const int n = (bid - 21245) * 4 + w;
        const float* row = wproj + (size_t)n * 1280;
        float s = 0.f;
        for (int t = lane; t < 1024; t += 64) s += row[t] * bo[t];
        #pragma unroll
        for (int off = 32; off > 0; off >>= 1) s += __shfl_down(s, off);
        if (lane == 0) beff[n] = bproj[n] + s;
    }
}

// ---------- 256x256 GEMM, 16 waves (4/SIMD), slot-XOR LDS, 4-slot ring (proven) ----------
template <int NT>
__global__ __launch_bounds__(1024, 4) void mm8_k(
    const u16* __restrict__ A, const u16* __restrict__ W,
    const float* __restrict__ bias,
    u16* __restrict__ o0, u16* __restrict__ o1, u16* __restrict__ o2,
    int K, int ntn)
{
    __shared__ alignas(16) u16 lds[65536];   // 4 slots x (A 8192 + B 8192) u16
    const int tid  = threadIdx.x;
    const int w    = tid >> 6;     // 0..15
    const int lane = tid & 63;
    const int l15  = lane & 15;
    const int lk   = lane >> 4;
    const int wr   = w >> 2;       // 0..3
    const int wc   = w & 3;        // 0..3

    const int nwg = gridDim.x;
    const int bid = blockIdx.x;
    const int e   = (bid & 7) * (nwg >> 3) + (bid >> 3);
    const int bm0 = (e / ntn) * 256;
    const int bn0 = (e % ntn) * 256;

    const int kc_l = (lane & 3) ^ ((lane >> 3) & 3);
    const u16* gsrc = (w < 8) ? A : W;
    const int rbase = (w < 8) ? bm0 : bn0;
    size_t src[2];
    #pragma unroll
    for (int i = 0; i < 2; ++i) {
        const int row = (w & 7) * 32 + i * 16 + (lane >> 2);
        src[i] = (size_t)(rbase + row) * K + kc_l * 8;
    }
    const int dstA = ((w < 8) ? 0 : 8192) + (w & 7) * 1024;

#define STAGE(t) { u16* d = lds + ((t) & 3) * 16384 + dstA;            \
    gload16(gsrc + src[0] + (size_t)(t) * 32, d);                      \
    gload16(gsrc + src[1] + (size_t)(t) * 32, d + 512); }

    const int rslot = (lk ^ ((l15 >> 1) & 3)) * 8;
    const int aoff = (wr * 64 + l15) * 32 + rslot;             // + mf*512
    const int boff = 8192 + (wc * 64 + l15) * 32 + rslot;      // + nf*512

    f32x4 acc[4][4] = {};

    STAGE(0); STAGE(1); STAGE(2);
    asm volatile("s_waitcnt vmcnt(4)" ::: "memory");
    __builtin_amdgcn_sched_barrier(0);
    __builtin_amdgcn_s_barrier();

    for (int t = 0; t < NT; ++t) {
        const u16* sa = lds + (t & 3) * 16384 + aoff;
        const u16* sb = lds + (t & 3) * 16384 + boff;
        bf16x8 af[4], bfr[4];
        #pragma unroll
        for (int nf = 0; nf < 4; ++nf) bfr[nf] = *(const bf16x8*)(sb + nf * 512);
        #pragma unroll
        for (int mf = 0; mf < 4; ++mf) af[mf] = *(const bf16x8*)(sa + mf * 512);
        if (t + 3 < NT) STAGE(t + 3);
        __builtin_amdgcn_s_setprio(1);
        #pragma unroll
        for (int mf = 0; mf < 4; ++mf)
            #pragma unroll
            for (int nf = 0; nf < 4; ++nf)
                acc[mf][nf] = __builtin_amdgcn_mfma_f32_16x16x32_bf16(af[mf], bfr[nf], acc[mf][nf], 0, 0, 0);
        __builtin_amdgcn_s_setprio(0);
        if (t < NT - 3)      { asm volatile("s_waitcnt vmcnt(4)" ::: "memory"); }
        else if (t == NT - 3){ asm volatile("s_waitcnt vmcnt(2)" ::: "memory"); }
        else if (t == NT - 2){ asm volatile("s_waitcnt vmcnt(0)" ::: "memory"); }
        __builtin_amdgcn_sched_barrier(0);
        __builtin_amdgcn_s_barrier();
    }
#undef STAGE

    const int plane = bn0 >> 10;
    u16* outp = plane == 0 ? o0 : (plane == 1 ? o1 : o2);
    const int cip0 = (bn0 & 1023) + wc * 64;
    const int colg = bn0 + wc * 64 + l15;
    float bsv[4];
    #pragma unroll
    for (int nf = 0; nf < 4; ++nf) bsv[nf] = bias[colg + nf * 16];
    const int erow = lane >> 3;
    const int echk = lane & 7;
    u16* wlds = lds + w * 2304;

    #pragma unroll
    for (int mf = 0; mf < 4; ++mf) {
        u16* pat = wlds + (mf & 1) * 1152;
        #pragma unroll
        for (int nf = 0; nf < 4; ++nf) {
            #pragma unroll
            for (int r = 0; r < 4; ++r) {
                const float val = acc[mf][nf][r] + bsv[nf];
                const float pv = __shfl_xor(val, 1, 64);
                if ((l15 & 1) == 0) {
                    const u32 pk = (u32)f2bf(val) | ((u32)f2bf(pv) << 16);
                    *(u32*)(pat + (lk * 4 + r) * 72 + nf * 16 + l15) = pk;
                }
            }
        }
        asm volatile("s_waitcnt lgkmcnt(0)" ::: "memory");
        __builtin_amdgcn_sched_barrier(0);
        #pragma unroll
        for (int j2 = 0; j2 < 2; ++j2) {
            const int rr = j2 * 8 + erow;
            const uint4 vv = *(const uint4*)(pat + rr * 72 + echk * 8);
            const int grow = bm0 + wr * 64 + mf * 16 + rr;
            *(uint4*)(outp + (size_t)grow * 1024 + cip0 + echk * 8) = vv;
        }
    }
}

// ---------- 128x128 GEMM, slot-XOR LDS, 4-slot ring prefetch (final + root) ----------
#define AM_PLAIN  0
#define AM_CONCAT 2
#define OM_BF16   0
#define OM_FINAL  1

template <int NT, int AMODE, int OMODE>
__global__ __launch_bounds__(256) void mm_k(
    const u16* __restrict__ A, const u16* __restrict__ W,
    const float* __restrict__ bias,
    u16* __restrict__ Ybf, float* __restrict__ Yf, float* __restrict__ Y2,
    int K, int ostride,
    const int* __restrict__ gidx, const u16* __restrict__ aux,
    const float* __restrict__ broot)
{
    constexpr int N = 1024;
    __shared__ alignas(16) u16 lds[32768];   // 4 slots x (A 4096 + B 4096) u16

    const int bid = blockIdx.x;
    if (OMODE == OM_FINAL && bid >= 512) {   // fused root: out2 row 0 = bias_root
        const int i = (bid - 512) * 256 + threadIdx.x;
        const int b = i >> 10, d = i & 1023;
        Y2[(size_t)b * (L_ + 1) * D_ + d] = broot[d];
        return;
    }

    const int tid  = threadIdx.x;
    const int wid  = tid >> 6;
    const int lane = tid & 63;
    const int l15  = lane & 15;
    const int lk   = lane >> 4;

    const int nwg = (OMODE == OM_FINAL) ? 512 : gridDim.x;
    const int e   = (bid & 7) * (nwg >> 3) + (bid >> 3);
    const int bm0 = (e >> 3) * 128;
    const int bn0 = (e & 7) * 128;

    const int kc_l = (lane & 3) ^ ((lane >> 3) & 3);
    long ga[2], gw[2], gt[2];
    #pragma unroll
    for (int i = 0; i < 2; ++i) {
        const int row = wid * 32 + i * 16 + (lane >> 2);
        if (AMODE == AM_CONCAT) {
            ga[i] = (long)(bm0 + row) * D_ + kc_l * 8;
            gt[i] = (long)gidx[bm0 + row] * WD_ + kc_l * 8;
        } else {
            ga[i] = (long)(bm0 + row) * K + kc_l * 8;
            gt[i] = 0;
        }
        gw[i] = (long)(bn0 + row) * K + kc_l * 8;
    }

#define MSTAGE(t) { const int k0t = (t) * 32;                              \
    u16* d  = lds + ((t) & 3) * 8192 + wid * 1024;                         \
    u16* db = d + 4096;                                                    \
    if (AMODE == AM_CONCAT && k0t >= D_) {                                 \
        gload16(aux + gt[0] + (k0t - D_), d);                              \
        gload16(aux + gt[1] + (k0t - D_), d + 512);                        \
    } else {                                                               \
        gload16(A + ga[0] + k0t, d);                                       \
        gload16(A + ga[1] + k0t, d + 512);                                 \
    }                                                                      \
    gload16(W + gw[0] + k0t, db);                                          \
    gload16(W + gw[1] + k0t, db + 512); }

    f32x4 acc[4][4] = {};

    const int moff = (wid >> 1) * 64;
    const int noff = (wid & 1) * 64;
    const int rslot = (lk ^ ((l15 >> 1) & 3)) * 8;
    const int aoff = (moff + l15) * 32 + rslot;
    const int boff = 4096 + (noff + l15) * 32 + rslot;

    MSTAGE(0); MSTAGE(1); MSTAGE(2);
    asm volatile("s_waitcnt vmcnt(8)" ::: "memory");
    __builtin_amdgcn_sched_barrier(0);
    __builtin_amdgcn_s_barrier();

    for (int t = 0; t < NT; ++t) {
        const u16* sa = lds + (t & 3) * 8192 + aoff;
        const u16* sb = lds + (t & 3) * 8192 + boff;
        bf16x8 af[4], bfr[4];
        #pragma unroll
        for (int j = 0; j < 4; ++j) bfr[j] = *(const bf16x8*)(sb + j * 512);
        #pragma unroll
        for (int i = 0; i < 4; ++i) af[i] = *(const bf16x8*)(sa + i * 512);
        if (t + 3 < NT) MSTAGE(t + 3);
        __builtin_amdgcn_s_setprio(1);
        #pragma unroll
        for (int i = 0; i < 4; ++i)
            #pragma unroll
            for (int j = 0; j < 4; ++j)
                acc[i][j] = __builtin_amdgcn_mfma_f32_16x16x32_bf16(af[i], bfr[j], acc[i][j], 0, 0, 0);
        __builtin_amdgcn_s_setprio(0);
        if (t < NT - 3)      { asm volatile("s_waitcnt vmcnt(8)" ::: "memory"); }
        else if (t == NT - 3){ asm volatile("s_waitcnt vmcnt(4)" ::: "memory"); }
        else if (t == NT - 2){ asm volatile("s_waitcnt vmcnt(0)" ::: "memory"); }
        __builtin_amdgcn_sched_barrier(0);
        __builtin_amdgcn_s_barrier();
    }
#undef MSTAGE

    #pragma unroll
    for (int j = 0; j < 4; ++j) {
        const int col = bn0 + noff + j * 16 + l15;
        const float bj = bias ? bias[col] : 0.f;
        #pragma unroll
        for (int i = 0; i < 4; ++i) {
            const int mrow = bm0 + moff + i * 16 + lk * 4;
            #pragma unroll
            for (int r = 0; r < 4; ++r) {
                const float val = acc[i][j][r] + bj;
                const long m = mrow + r;
                if (OMODE == OM_BF16) {
                    Ybf[m * (long)ostride + col] = f2bf(val);
                } else {
                    Yf[m * (long)N + col] = val;
                    const long bb = m >> 9, ll = m & 511;
                    Y2[((bb * (L_ + 1)) + ll + 1) * (long)D_ + col] = val;
                }
            }
        }
    }
}

// ---------- merged: sparse masked attention (blocks 0..8191) + Weff GEMM (8192..8255) ----------
__global__ __launch_bounds__(256) void aw_k(
    const u16* __restrict__ kb, const u16* __restrict__ vb,
    const int* __restrict__ sem_syn, const int* __restrict__ to_sem,
    const u16* __restrict__ qf, u16* __restrict__ ctx,
    const u16* __restrict__ wp1, const u16* __restrict__ wot,
    u16* __restrict__ wfin)
{
    __shared__ alignas(16) unsigned char shm[36928];
    const int bid = blockIdx.x;
    const int tid = threadIdx.x;

    if (bid >= 8192) {
        // ---- Weff = wp1 @ wot^T -> wfin cols 0..1023 (stride 1280), 2-slot ring ----
        u16* lds = (u16*)shm;                 // 2 slots x (A 4096 + B 4096) u16 = 32KB
        const int bid2 = bid - 8192;          // 0..63
        const int wid  = tid >> 6;
        const int lane = tid & 63;
        const int l15  = lane & 15;
        const int lk   = lane >> 4;
        const int e    = (bid2 & 7) * 8 + (bid2 >> 3);
        const int bm0  = (e >> 3) * 128;
        const int bn0  = (e & 7) * 128;
        const int K    = 1024;

        const int kc_l = (lane & 3) ^ ((lane >> 3) & 3);
        long ga[2], gw[2];
        #pragma unroll
        for (int i = 0; i < 2; ++i) {
            const int row = wid * 32 + i * 16 + (lane >> 2);
            ga[i] = (long)(bm0 + row) * K + kc_l * 8;
            gw[i] = (long)(bn0 + row) * K + kc_l * 8;
        }

#define WSTAGE(t) { u16* d = lds + ((t) & 1) * 8192 + wid * 1024;      \
    gload16(wp1 + ga[0] + (size_t)(t) * 32, d);                        \
    gload16(wp1 + ga[1] + (size_t)(t) * 32, d + 512);                  \
    gload16(wot + gw[0] + (size_t)(t) * 32, d + 4096);                 \
    gload16(wot + gw[1] + (size_t)(t) * 32, d + 4608); }

        f32x4 acc[4][4] = {};
        const int moff = (wid >> 1) * 64;
        const int noff = (wid & 1) * 64;
        const int rslot = (lk ^ ((l15 >> 1) & 3)) * 8;
        const int aoff = (moff + l15) * 32 + rslot;
        const int boff = 4096 + (noff + l15) * 32 + rslot;

        WSTAGE(0);
        for (int t = 0; t < 32; ++t) {
            if (t + 1 < 32) {
                WSTAGE(t + 1);
                asm volatile("s_waitcnt vmcnt(4)" ::: "memory");
            } else {
                asm volatile("s_waitcnt vmcnt(0)" ::: "memory");
            }
            __builtin_amdgcn_sched_barrier(0);
            __builtin_amdgcn_s_barrier();
            const u16* sa = lds + (t & 1) * 8192 + aoff;
            const u16* sb = lds + (t & 1) * 8192 + boff;
            bf16x8 af[4], bfr[4];
            #pragma unroll
            for (int j = 0; j < 4; ++j) bfr[j] = *(const bf16x8*)(sb + j * 512);
            #pragma unroll
            for (int i = 0; i < 4; ++i) af[i] = *(const bf16x8*)(sa + i * 512);
            #pragma unroll
            for (int i = 0; i < 4; ++i)
                #pragma unroll
                for (int j = 0; j < 4; ++j)
                    acc[i][j] = __builtin_amdgcn_mfma_f32_16x16x32_bf16(af[i], bfr[j], acc[i][j], 0, 0, 0);
            __builtin_amdgcn_s_barrier();
        }
#undef WSTAGE

        #pragma unroll
        for (int j = 0; j < 4; ++j) {
            const int col = bn0 + noff + j * 16 + l15;
            #pragma unroll
            for (int i = 0; i < 4; ++i) {
                const int mrow = bm0 + moff + i * 16 + lk * 4;
                #pragma unroll
                for (int r = 0; r < 4; ++r)
                    wfin[(long)(mrow + r) * 1280 + col] = f2bf(acc[i][j][r]);
            }
        }
        return;
    }

    // ---- sparse masked attention ----
    int*   list = (int*)shm;                        // 1024 ints
    float* sc   = (float*)(shm + 4096);             // [8][1024]
    int*   wcnt = (int*)(shm + 4096 + 32768);       // 16 ints

    const int b   = bid >> 9;
    const int l   = bid & 511;
    const int wvi = tid >> 6;
    const int ln  = tid & 63;

    const int tosem = to_sem[bid];
    const ushort4 qu = *(const ushort4*)(qf + ((size_t)b * S_ + tosem) * D_ + tid * 4);
    const float4 qv = make_float4(bf2f(qu.x), bf2f(qu.y), bf2f(qu.z), bf2f(qu.w));

    bool al[4];
    #pragma unroll
    for (int j = 0; j < 4; ++j) {
        const int s = tid * 4 + j;
        const int a = sem_syn[b * S_ + s];
        al[j] = (a == l + 1) || (s == tosem);
    }
    u64 msk[4];
    #pragma unroll
    for (int j = 0; j < 4; ++j) msk[j] = __ballot(al[j]);
    if (ln == 0) {
        #pragma unroll
        for (int j = 0; j < 4; ++j) wcnt[wvi * 4 + j] = __popcll(msk[j]);
    }
    __syncthreads();
    int mybase[4];
    {
        int tot = 0;
        #pragma unroll
        for (int i2 = 0; i2 < 16; ++i2) {
            const int c2 = wcnt[i2];
            #pragma unroll
            for (int j2 = 0; j2 < 4; ++j2)
                if (i2 == wvi * 4 + j2) mybase[j2] = tot;
            tot += c2;
        }
    }
    const u64 lmlt = (1ull << ln) - 1ull;
    #pragma unroll
    for (int j = 0; j < 4; ++j)
        if (al[j]) list[mybase[j] + __popcll(msk[j] & lmlt)] = tid * 4 + j;
    int n = 0;
    #pragma unroll
    for (int i2 = 0; i2 < 16; ++i2) n += wcnt[i2];
    __syncthreads();

    const int g = tid >> 5;
    const int lane = tid & 31;
    for (int i = 0; i < n; ++i) {
        const u16* krow = kb + ((size_t)b * S_ + list[i]) * D_;
        const ushort4 ku = *(const ushort4*)(krow + tid * 4);
        float p = bf2f(ku.x) * qv.x + bf2f(ku.y) * qv.y + bf2f(ku.z) * qv.z + bf2f(ku.w) * qv.w;
        #pragma unroll
        for (int off = 16; off > 0; off >>= 1) p += __shfl_down(p, off, 32);
        if (lane == 0) sc[g * 1024 + i] = p;
    }
    __syncthreads();

    float mx = -3.0e38f;
    for (int i = lane; i < n; i += 32) mx = fmaxf(mx, sc[g * 1024 + i]);
    #pragma unroll
    for (int off = 16; off > 0; off >>= 1) mx = fmaxf(mx, __shfl_xor(mx, off, 32));
    float sum = 0.f;
    for (int i = lane; i < n; i += 32) {
        const float e = expf(sc[g * 1024 + i] - mx);
        sc[g * 1024 + i] = e;
        sum += e;
    }
    #pragma unroll
    for (int off = 16; off > 0; off >>= 1) sum += __shfl_xor(sum, off, 32);
    const float inv = 1.0f / sum;
    __syncthreads();

    float4 a4 = make_float4(0.f, 0.f, 0.f, 0.f);
    for (int i = 0; i < n; ++i) {
        const float wgt = sc[g * 1024 + i] * inv;
        const u16* vrow = vb + ((size_t)b * S_ + list[i]) * D_;
        const ushort4 vu = *(const ushort4*)(vrow + tid * 4);
        a4.x = fmaf(wgt, bf2f(vu.x), a4.x);
        a4.y = fmaf(wgt, bf2f(vu.y), a4.y);
        a4.z = fmaf(wgt, bf2f(vu.z), a4.z);
        a4.w = fmaf(wgt, bf2f(vu.w), a4.w);
    }
    ushort4 o;
    o.x = f2bf(a4.x); o.y = f2bf(a4.y); o.z = f2bf(a4.z); o.w = f2bf(a4.w);
    *(ushort4*)(ctx + (size_t)bid * D_ + tid * 4) = o;
}

extern "C" void kernel_launch(void* const* d_in, const int* in_sizes, int n_in,
                              void* d_out, int out_size, void* d_ws, size_t ws_size,
                              hipStream_t stream)
{
    const float* enc    = (const float*)d_in[0];
    const int*   to_sem = (const int*)  d_in[1];
    const int*   tstype = (const int*)  d_in[2];
    const int*   semsyn = (const int*)  d_in[3];
    const float* wq = (const float*)d_in[4];
    const float* bq = (const float*)d_in[5];
    const float* wk = (const float*)d_in[6];
    const float* bk = (const float*)d_in[7];
    const float* wv = (const float*)d_in[8];
    const float* bv = (const float*)d_in[9];
    const float* wo = (const float*)d_in[10];
    const float* bo = (const float*)d_in[11];
    const float* temb  = (const float*)d_in[12];
    const float* wproj = (const float*)d_in[13];
    const float* bproj = (const float*)d_in[14];
    const float* broot = (const float*)d_in[15];

    float* out1 = (float*)d_out;
    float* out2 = out1 + (size_t)B_ * L_ * D_;

    unsigned char* ws = (unsigned char*)d_ws;
    u16*   enc_bf = (u16*)(ws);
    u16*   k_bf   = (u16*)(ws + (32ull << 20));
    u16*   wkvq   = (u16*)(ws + (64ull << 20));          // [3072 x 1024]
    u16*   wot    = (u16*)(ws + (70ull << 20));          // wo^T bf16
    u16*   wp1    = (u16*)(ws + (72ull << 20));          // wproj cols 0..1023
    u16*   wfin   = (u16*)(ws + (74ull << 20));          // [1024 x 1280]
    float* beff   = (float*)(ws + (77ull << 20));
    float* bkvq   = (float*)(ws + (77ull << 20) + 8192);
    u16*   ctx_bf = (u16*)(ws + (78ull << 20));          // [8192 x 1024]
    u16*   te_bf  = (u16*)(ws + (94ull << 20));          // [1000 x 256]

    u16* v_bf = (u16*)d_out;
    u16* q_bf = (u16*)((unsigned char*)d_out + (32ull << 20));

    const float qscale = 0.08838834764831845f;   // DH^-0.5
    dim3 blk(256);

    prep_k<<<dim3(21501), blk, 0, stream>>>(
        enc, wk, wv, wq, temb, bk, bv, bq, wo, wproj, bo, bproj,
        enc_bf, wkvq, te_bf, bkvq, wot, wp1, wfin, beff, qscale);

    // fused K|V|Q GEMM: [16384 x 1024] @ [3072 x 1024]^T
    mm8_k<32><<<dim3(768), dim3(1024), 0, stream>>>(
        enc_bf, wkvq, bkvq, k_bf, v_bf, q_bf, 1024, 12);

    // merged: sparse masked attention + Weff GEMM
    aw_k<<<dim3(8256), blk, 0, stream>>>(
        k_bf, v_bf, semsyn, to_sem, q_bf, ctx_bf, wp1, wot, wfin);

    // final: [ctx | temb[tstype]] @ wfin^T + beff -> out1, out2 rows 1..L ; blocks 512.. do root
    mm_k<40, AM_CONCAT, OM_FINAL><<<dim3(576), blk, 0, stream>>>(
        ctx_bf, wfin, beff, nullptr, out1, out2, KP_, 1024, tstype, te_bf, broot);
}

// Round 14
// 210.230 us; speedup vs baseline: 1.0973x; 1.0973x over previous
//
#include <hip/hip_runtime.h>

typedef unsigned short u16;
typedef unsigned int   u32;
typedef unsigned long long u64;
typedef __bf16 bf16x8 __attribute__((ext_vector_type(8)));
typedef float  f32x4  __attribute__((ext_vector_type(4)));

#define B_  16
#define S_  1024
#define L_  512
#define D_  1024
#define H_  8
#define WD_ 256
#define KP_ (D_ + WD_)

__device__ __forceinline__ u16 f2bf(float f) {
    u32 u = __float_as_uint(f);
    return (u16)((u + 0x7FFFu + ((u >> 16) & 1u)) >> 16);
}
__device__ __forceinline__ float bf2f(u16 h) {
    return __uint_as_float(((u32)h) << 16);
}
__device__ __forceinline__ void gload16(const void* g, void* l) {
    __builtin_amdgcn_global_load_lds(
        (const __attribute__((address_space(1))) u32*)(unsigned long long)(g),
        (__attribute__((address_space(3))) u32*)(unsigned long long)(l),
        16, 0, 0);
}

// ---------- single fused prep kernel ----------
__global__ __launch_bounds__(256) void prep_k(
    const float* __restrict__ enc,
    const float* __restrict__ wk, const float* __restrict__ wv,
    const float* __restrict__ wq, const float* __restrict__ te,
    const float* __restrict__ bk, const float* __restrict__ bv,
    const float* __restrict__ bq,
    const float* __restrict__ wo, const float* __restrict__ wproj,
    const float* __restrict__ bo, const float* __restrict__ bproj,
    u16* __restrict__ enc_bf, u16* __restrict__ wkvq, u16* __restrict__ te_bf,
    float* __restrict__ bkvq, u16* __restrict__ wot,
    u16* __restrict__ wp1, u16* __restrict__ wfin,
    float* __restrict__ beff, float qs)
{
    __shared__ float tile[64][65];
    const int bid = blockIdx.x;
    if (bid < 16384) {
        const int i = (bid * 256 + threadIdx.x) * 4;
        const float4 v = *(const float4*)(enc + i);
        ushort4 o;
        o.x = f2bf(v.x); o.y = f2bf(v.y); o.z = f2bf(v.z); o.w = f2bf(v.w);
        *(ushort4*)(enc_bf + i) = o;
    } else if (bid < 19456) {
        const int b2 = bid - 16384;
        const int plane = b2 >> 10;
        const int i = ((b2 & 1023) * 256 + threadIdx.x) * 4;
        const float* src = plane == 0 ? wk : (plane == 1 ? wv : wq);
        const float s = plane == 2 ? qs : 1.0f;
        const float4 v = *(const float4*)(src + i);
        ushort4 o;
        o.x = f2bf(v.x * s); o.y = f2bf(v.y * s); o.z = f2bf(v.z * s); o.w = f2bf(v.w * s);
        *(ushort4*)(wkvq + (size_t)plane * 1048576 + i) = o;
    } else if (bid < 19706) {
        const int i = ((bid - 19456) * 256 + threadIdx.x) * 4;
        if (i < 256000) {
            const float4 v = *(const float4*)(te + i);
            ushort4 o;
            o.x = f2bf(v.x); o.y = f2bf(v.y); o.z = f2bf(v.z); o.w = f2bf(v.w);
            *(ushort4*)(te_bf + i) = o;
        }
    } else if (bid < 19709) {
        const int i = (bid - 19706) * 1024 + threadIdx.x * 4;
        #pragma unroll
        for (int j = 0; j < 4; ++j) {
            const int idx = i + j;
            bkvq[idx] = (idx < 1024) ? bk[idx]
                      : (idx < 2048 ? bv[idx - 1024] : bq[idx - 2048] * qs);
        }
    } else if (bid < 19965) {
        const int cid = bid - 19709;
        const int t0 = (cid & 15) * 64;
        const int k0 = (cid >> 4) * 64;
        const int tr = threadIdx.x >> 4;
        const int tc = threadIdx.x & 15;
        #pragma unroll
        for (int i = 0; i < 4; ++i) {
            const int r = tr + i * 16;
            const float4 v = *(const float4*)(wo + (size_t)(t0 + r) * 1024 + k0 + tc * 4);
            tile[r][tc * 4 + 0] = v.x; tile[r][tc * 4 + 1] = v.y;
            tile[r][tc * 4 + 2] = v.z; tile[r][tc * 4 + 3] = v.w;
        }
        __syncthreads();
        #pragma unroll
        for (int i = 0; i < 4; ++i) {
            const int r = tr + i * 16;
            ushort4 o;
            o.x = f2bf(tile[tc * 4 + 0][r]);
            o.y = f2bf(tile[tc * 4 + 1][r]);
            o.z = f2bf(tile[tc * 4 + 2][r]);
            o.w = f2bf(tile[tc * 4 + 3][r]);
            *(ushort4*)(wot + (size_t)(k0 + r) * 1024 + t0 + tc * 4) = o;
        }
    } else if (bid < 21245) {
        const int i = ((bid - 19965) * 256 + threadIdx.x) * 4;
        const int n = i / 1280, c = i % 1280;
        const float4 v = *(const float4*)(wproj + i);
        ushort4 o;
        o.x = f2bf(v.x); o.y = f2bf(v.y); o.z = f2bf(v.z); o.w = f2bf(v.w);
        if (c < 1024) *(ushort4*)(wp1 + (size_t)n * 1024 + c) = o;
        else          *(ushort4*)(wfin + (size_t)n * 1280 + c) = o;
    } else {
        const int w = threadIdx.x >> 6, lane = threadIdx.x & 63;
        const int n = (bid - 21245) * 4 + w;
        const float* row = wproj + (size_t)n * 1280;
        float s = 0.f;
        for (int t = lane; t < 1024; t += 64) s += row[t] * bo[t];
        #pragma unroll
        for (int off = 32; off > 0; off >>= 1) s += __shfl_down(s, off);
        if (lane == 0) beff[n] = bproj[n] + s;
    }
}

// ---------- 256x256 GEMM, 16 waves (4/SIMD), slot-XOR LDS, 4-slot ring (proven) ----------
template <int NT>
__global__ __launch_bounds__(1024, 4) void mm8_k(
    const u16* __restrict__ A, const u16* __restrict__ W,
    const float* __restrict__ bias,
    u16* __restrict__ o0, u16* __restrict__ o1,
    int K, int ntn)
{
    __shared__ alignas(16) u16 lds[65536];   // 4 slots x (A 8192 + B 8192) u16
    const int tid  = threadIdx.x;
    const int w    = tid >> 6;     // 0..15
    const int lane = tid & 63;
    const int l15  = lane & 15;
    const int lk   = lane >> 4;
    const int wr   = w >> 2;       // 0..3
    const int wc   = w & 3;        // 0..3

    const int nwg = gridDim.x;
    const int bid = blockIdx.x;
    const int e   = (bid & 7) * (nwg >> 3) + (bid >> 3);
    const int bm0 = (e / ntn) * 256;
    const int bn0 = (e % ntn) * 256;

    const int kc_l = (lane & 3) ^ ((lane >> 3) & 3);
    const u16* gsrc = (w < 8) ? A : W;
    const int rbase = (w < 8) ? bm0 : bn0;
    size_t src[2];
    #pragma unroll
    for (int i = 0; i < 2; ++i) {
        const int row = (w & 7) * 32 + i * 16 + (lane >> 2);
        src[i] = (size_t)(rbase + row) * K + kc_l * 8;
    }
    const int dstA = ((w < 8) ? 0 : 8192) + (w & 7) * 1024;

#define STAGE(t) { u16* d = lds + ((t) & 3) * 16384 + dstA;            \
    gload16(gsrc + src[0] + (size_t)(t) * 32, d);                      \
    gload16(gsrc + src[1] + (size_t)(t) * 32, d + 512); }

    const int rslot = (lk ^ ((l15 >> 1) & 3)) * 8;
    const int aoff = (wr * 64 + l15) * 32 + rslot;             // + mf*512
    const int boff = 8192 + (wc * 64 + l15) * 32 + rslot;      // + nf*512

    f32x4 acc[4][4] = {};

    STAGE(0); STAGE(1); STAGE(2);
    asm volatile("s_waitcnt vmcnt(4)" ::: "memory");
    __builtin_amdgcn_sched_barrier(0);
    __builtin_amdgcn_s_barrier();

    for (int t = 0; t < NT; ++t) {
        const u16* sa = lds + (t & 3) * 16384 + aoff;
        const u16* sb = lds + (t & 3) * 16384 + boff;
        bf16x8 af[4], bfr[4];
        #pragma unroll
        for (int nf = 0; nf < 4; ++nf) bfr[nf] = *(const bf16x8*)(sb + nf * 512);
        #pragma unroll
        for (int mf = 0; mf < 4; ++mf) af[mf] = *(const bf16x8*)(sa + mf * 512);
        if (t + 3 < NT) STAGE(t + 3);
        __builtin_amdgcn_s_setprio(1);
        #pragma unroll
        for (int mf = 0; mf < 4; ++mf)
            #pragma unroll
            for (int nf = 0; nf < 4; ++nf)
                acc[mf][nf] = __builtin_amdgcn_mfma_f32_16x16x32_bf16(af[mf], bfr[nf], acc[mf][nf], 0, 0, 0);
        __builtin_amdgcn_s_setprio(0);
        if (t < NT - 3)      { asm volatile("s_waitcnt vmcnt(4)" ::: "memory"); }
        else if (t == NT - 3){ asm volatile("s_waitcnt vmcnt(2)" ::: "memory"); }
        else if (t == NT - 2){ asm volatile("s_waitcnt vmcnt(0)" ::: "memory"); }
        __builtin_amdgcn_sched_barrier(0);
        __builtin_amdgcn_s_barrier();
    }
#undef STAGE

    const int plane = bn0 >> 10;
    u16* outp = plane == 0 ? o0 : o1;
    const int cip0 = (bn0 & 1023) + wc * 64;
    const int colg = bn0 + wc * 64 + l15;
    float bsv[4];
    #pragma unroll
    for (int nf = 0; nf < 4; ++nf) bsv[nf] = bias[colg + nf * 16];
    const int erow = lane >> 3;
    const int echk = lane & 7;
    u16* wlds = lds + w * 2304;

    #pragma unroll
    for (int mf = 0; mf < 4; ++mf) {
        u16* pat = wlds + (mf & 1) * 1152;
        #pragma unroll
        for (int nf = 0; nf < 4; ++nf) {
            #pragma unroll
            for (int r = 0; r < 4; ++r) {
                const float val = acc[mf][nf][r] + bsv[nf];
                const float pv = __shfl_xor(val, 1, 64);
                if ((l15 & 1) == 0) {
                    const u32 pk = (u32)f2bf(val) | ((u32)f2bf(pv) << 16);
                    *(u32*)(pat + (lk * 4 + r) * 72 + nf * 16 + l15) = pk;
                }
            }
        }
        asm volatile("s_waitcnt lgkmcnt(0)" ::: "memory");
        __builtin_amdgcn_sched_barrier(0);
        #pragma unroll
        for (int j2 = 0; j2 < 2; ++j2) {
            const int rr = j2 * 8 + erow;
            const uint4 vv = *(const uint4*)(pat + rr * 72 + echk * 8);
            const int grow = bm0 + wr * 64 + mf * 16 + rr;
            *(uint4*)(outp + (size_t)grow * 1024 + cip0 + echk * 8) = vv;
        }
    }
}

// ---------- 128x128 GEMM, slot-XOR LDS, 4-slot ring prefetch ----------
#define AM_PLAIN  0
#define AM_GATHER 1
#define AM_CONCAT 2
#define OM_BF16   0
#define OM_FINAL  1

template <int NT, int AMODE, int OMODE>
__global__ __launch_bounds__(256) void mm_k(
    const u16* __restrict__ A, const u16* __restrict__ W,
    const float* __restrict__ bias,
    u16* __restrict__ Ybf, float* __restrict__ Yf, float* __restrict__ Y2,
    int K, int ostride,
    const int* __restrict__ gidx, const u16* __restrict__ aux,
    const float* __restrict__ broot)
{
    constexpr int N = 1024;
    __shared__ alignas(16) u16 lds[32768];   // 4 slots x (A 4096 + B 4096) u16

    const int bid = blockIdx.x;
    if (OMODE == OM_FINAL && bid >= 512) {   // fused root: out2 row 0 = bias_root
        const int i = (bid - 512) * 256 + threadIdx.x;
        const int b = i >> 10, d = i & 1023;
        Y2[(size_t)b * (L_ + 1) * D_ + d] = broot[d];
        return;
    }

    const int tid  = threadIdx.x;
    const int wid  = tid >> 6;
    const int lane = tid & 63;
    const int l15  = lane & 15;
    const int lk   = lane >> 4;

    const int nwg = (OMODE == OM_FINAL) ? 512 : gridDim.x;
    const int e   = (bid & 7) * (nwg >> 3) + (bid >> 3);
    const int bm0 = (e >> 3) * 128;
    const int bn0 = (e & 7) * 128;

    const int kc_l = (lane & 3) ^ ((lane >> 3) & 3);
    long ga[2], gw[2], gt[2];
    #pragma unroll
    for (int i = 0; i < 2; ++i) {
        const int row = wid * 32 + i * 16 + (lane >> 2);
        const int m = bm0 + row;
        if (AMODE == AM_CONCAT) {
            ga[i] = (long)m * D_ + kc_l * 8;
            gt[i] = (long)gidx[m] * WD_ + kc_l * 8;
        } else if (AMODE == AM_GATHER) {
            ga[i] = ((long)(m >> 9) * S_ + gidx[m]) * D_ + kc_l * 8;
            gt[i] = 0;
        } else {
            ga[i] = (long)m * K + kc_l * 8;
            gt[i] = 0;
        }
        gw[i] = (long)(bn0 + row) * K + kc_l * 8;
    }

#define MSTAGE(t) { const int k0t = (t) * 32;                              \
    u16* d  = lds + ((t) & 3) * 8192 + wid * 1024;                         \
    u16* db = d + 4096;                                                    \
    if (AMODE == AM_CONCAT && k0t >= D_) {                                 \
        gload16(aux + gt[0] + (k0t - D_), d);                              \
        gload16(aux + gt[1] + (k0t - D_), d + 512);                        \
    } else {                                                               \
        gload16(A + ga[0] + k0t, d);                                       \
        gload16(A + ga[1] + k0t, d + 512);                                 \
    }                                                                      \
    gload16(W + gw[0] + k0t, db);                                          \
    gload16(W + gw[1] + k0t, db + 512); }

    f32x4 acc[4][4] = {};

    const int moff = (wid >> 1) * 64;
    const int noff = (wid & 1) * 64;
    const int rslot = (lk ^ ((l15 >> 1) & 3)) * 8;
    const int aoff = (moff + l15) * 32 + rslot;
    const int boff = 4096 + (noff + l15) * 32 + rslot;

    MSTAGE(0); MSTAGE(1); MSTAGE(2);
    asm volatile("s_waitcnt vmcnt(8)" ::: "memory");
    __builtin_amdgcn_sched_barrier(0);
    __builtin_amdgcn_s_barrier();

    for (int t = 0; t < NT; ++t) {
        const u16* sa = lds + (t & 3) * 8192 + aoff;
        const u16* sb = lds + (t & 3) * 8192 + boff;
        bf16x8 af[4], bfr[4];
        #pragma unroll
        for (int j = 0; j < 4; ++j) bfr[j] = *(const bf16x8*)(sb + j * 512);
        #pragma unroll
        for (int i = 0; i < 4; ++i) af[i] = *(const bf16x8*)(sa + i * 512);
        if (t + 3 < NT) MSTAGE(t + 3);
        __builtin_amdgcn_s_setprio(1);
        #pragma unroll
        for (int i = 0; i < 4; ++i)
            #pragma unroll
            for (int j = 0; j < 4; ++j)
                acc[i][j] = __builtin_amdgcn_mfma_f32_16x16x32_bf16(af[i], bfr[j], acc[i][j], 0, 0, 0);
        __builtin_amdgcn_s_setprio(0);
        if (t < NT - 3)      { asm volatile("s_waitcnt vmcnt(8)" ::: "memory"); }
        else if (t == NT - 3){ asm volatile("s_waitcnt vmcnt(4)" ::: "memory"); }
        else if (t == NT - 2){ asm volatile("s_waitcnt vmcnt(0)" ::: "memory"); }
        __builtin_amdgcn_sched_barrier(0);
        __builtin_amdgcn_s_barrier();
    }
#undef MSTAGE

    #pragma unroll
    for (int j = 0; j < 4; ++j) {
        const int col = bn0 + noff + j * 16 + l15;
        const float bj = bias ? bias[col] : 0.f;
        #pragma unroll
        for (int i = 0; i < 4; ++i) {
            const int mrow = bm0 + moff + i * 16 + lk * 4;
            #pragma unroll
            for (int r = 0; r < 4; ++r) {
                const float val = acc[i][j][r] + bj;
                const long m = mrow + r;
                if (OMODE == OM_BF16) {
                    Ybf[m * (long)ostride + col] = f2bf(val);
                } else {
                    Yf[m * (long)N + col] = val;
                    const long bb = m >> 9, ll = m & 511;
                    Y2[((bb * (L_ + 1)) + ll + 1) * (long)D_ + col] = val;
                }
            }
        }
    }
}

// ---------- sparse masked attention (ballot compaction; q indexed by (b,l)) ----------
__global__ __launch_bounds__(256) void attn_k(
    const u16* __restrict__ kb, const u16* __restrict__ vb,
    const int* __restrict__ sem_syn, const int* __restrict__ to_sem,
    const u16* __restrict__ qf, u16* __restrict__ ctx)
{
    __shared__ int   list[S_];
    __shared__ float sc[H_][S_];
    __shared__ int   wcnt[16];

    const int bl  = blockIdx.x;
    const int b   = bl >> 9;
    const int l   = bl & 511;
    const int tid = threadIdx.x;
    const int wvi = tid >> 6;
    const int ln  = tid & 63;

    const int tosem = to_sem[bl];
    const ushort4 qu = *(const ushort4*)(qf + (size_t)bl * D_ + tid * 4);
    const float4 qv = make_float4(bf2f(qu.x), bf2f(qu.y), bf2f(qu.z), bf2f(qu.w));

    bool al[4];
    #pragma unroll
    for (int j = 0; j < 4; ++j) {
        const int s = tid * 4 + j;
        const int a = sem_syn[b * S_ + s];
        al[j] = (a == l + 1) || (s == tosem);
    }
    u64 msk[4];
    #pragma unroll
    for (int j = 0; j < 4; ++j) msk[j] = __ballot(al[j]);
    if (ln == 0) {
        #pragma unroll
        for (int j = 0; j < 4; ++j) wcnt[wvi * 4 + j] = __popcll(msk[j]);
    }
    __syncthreads();
    int mybase[4];
    {
        int tot = 0;
        #pragma unroll
        for (int i2 = 0; i2 < 16; ++i2) {
            const int c2 = wcnt[i2];
            #pragma unroll
            for (int j2 = 0; j2 < 4; ++j2)
                if (i2 == wvi * 4 + j2) mybase[j2] = tot;
            tot += c2;
        }
    }
    const u64 lmlt = (1ull << ln) - 1ull;
    #pragma unroll
    for (int j = 0; j < 4; ++j)
        if (al[j]) list[mybase[j] + __popcll(msk[j] & lmlt)] = tid * 4 + j;
    int n = 0;
    #pragma unroll
    for (int i2 = 0; i2 < 16; ++i2) n += wcnt[i2];
    __syncthreads();

    const int g = tid >> 5;
    const int lane = tid & 31;
    for (int i = 0; i < n; ++i) {
        const u16* krow = kb + ((size_t)b * S_ + list[i]) * D_;
        const ushort4 ku = *(const ushort4*)(krow + tid * 4);
        float p = bf2f(ku.x) * qv.x + bf2f(ku.y) * qv.y + bf2f(ku.z) * qv.z + bf2f(ku.w) * qv.w;
        #pragma unroll
        for (int off = 16; off > 0; off >>= 1) p += __shfl_down(p, off, 32);
        if (lane == 0) sc[g][i] = p;
    }
    __syncthreads();

    float mx = -3.0e38f;
    for (int i = lane; i < n; i += 32) mx = fmaxf(mx, sc[g][i]);
    #pragma unroll
    for (int off = 16; off > 0; off >>= 1) mx = fmaxf(mx, __shfl_xor(mx, off, 32));
    float sum = 0.f;
    for (int i = lane; i < n; i += 32) {
        const float e = expf(sc[g][i] - mx);
        sc[g][i] = e;
        sum += e;
    }
    #pragma unroll
    for (int off = 16; off > 0; off >>= 1) sum += __shfl_xor(sum, off, 32);
    const float inv = 1.0f / sum;
    __syncthreads();

    float4 a4 = make_float4(0.f, 0.f, 0.f, 0.f);
    for (int i = 0; i < n; ++i) {
        const float wgt = sc[g][i] * inv;
        const u16* vrow = vb + ((size_t)b * S_ + list[i]) * D_;
        const ushort4 vu = *(const ushort4*)(vrow + tid * 4);
        a4.x = fmaf(wgt, bf2f(vu.x), a4.x);
        a4.y = fmaf(wgt, bf2f(vu.y), a4.y);
        a4.z = fmaf(wgt, bf2f(vu.z), a4.z);
        a4.w = fmaf(wgt, bf2f(vu.w), a4.w);
    }
    ushort4 o;
    o.x = f2bf(a4.x); o.y = f2bf(a4.y); o.z = f2bf(a4.z); o.w = f2bf(a4.w);
    *(ushort4*)(ctx + (size_t)bl * D_ + tid * 4) = o;
}

extern "C" void kernel_launch(void* const* d_in, const int* in_sizes, int n_in,
                              void* d_out, int out_size, void* d_ws, size_t ws_size,
                              hipStream_t stream)
{
    const float* enc    = (const float*)d_in[0];
    const int*   to_sem = (const int*)  d_in[1];
    const int*   tstype = (const int*)  d_in[2];
    const int*   semsyn = (const int*)  d_in[3];
    const float* wq = (const float*)d_in[4];
    const float* bq = (const float*)d_in[5];
    const float* wk = (const float*)d_in[6];
    const float* bk = (const float*)d_in[7];
    const float* wv = (const float*)d_in[8];
    const float* bv = (const float*)d_in[9];
    const float* wo = (const float*)d_in[10];
    const float* bo = (const float*)d_in[11];
    const float* temb  = (const float*)d_in[12];
    const float* wproj = (const float*)d_in[13];
    const float* bproj = (const float*)d_in[14];
    const float* broot = (const float*)d_in[15];

    float* out1 = (float*)d_out;
    float* out2 = out1 + (size_t)B_ * L_ * D_;

    unsigned char* ws = (unsigned char*)d_ws;
    u16*   enc_bf = (u16*)(ws);
    u16*   k_bf   = (u16*)(ws + (32ull << 20));
    u16*   wkvq   = (u16*)(ws + (64ull << 20));          // [3072 x 1024]
    u16*   wot    = (u16*)(ws + (70ull << 20));          // wo^T bf16
    u16*   wp1    = (u16*)(ws + (72ull << 20));          // wproj cols 0..1023
    u16*   wfin   = (u16*)(ws + (74ull << 20));          // [1024 x 1280]
    float* beff   = (float*)(ws + (77ull << 20));
    float* bkvq   = (float*)(ws + (77ull << 20) + 8192);
    u16*   ctx_bf = (u16*)(ws + (78ull << 20));          // [8192 x 1024]
    u16*   te_bf  = (u16*)(ws + (94ull << 20));          // [1000 x 256]

    u16* v_bf = (u16*)d_out;                                    // 32MB scratch in out
    u16* q_bf = (u16*)((unsigned char*)d_out + (32ull << 20));  // 16MB ([8192 x 1024])

    const float qscale = 0.08838834764831845f;   // DH^-0.5
    dim3 blk(256);

    prep_k<<<dim3(21501), blk, 0, stream>>>(
        enc, wk, wv, wq, temb, bk, bv, bq, wo, wproj, bo, bproj,
        enc_bf, wkvq, te_bf, bkvq, wot, wp1, wfin, beff, qscale);

    // fused K|V GEMM: [16384 x 1024] @ [2048 x 1024]^T
    mm8_k<32><<<dim3(512), dim3(1024), 0, stream>>>(
        enc_bf, wkvq, bkvq, k_bf, v_bf, 1024, 8);

    // gathered Q GEMM: q[b,l] = enc_bf[b, to_sem[b,l]] @ (wq*s)^T + bq*s
    mm_k<32, AM_GATHER, OM_BF16><<<dim3(512), blk, 0, stream>>>(
        enc_bf, wkvq + 2097152, bkvq + 2048, q_bf, nullptr, nullptr,
        1024, 1024, to_sem, nullptr, nullptr);

    // Weff = Wp1 @ wo -> wfin cols 0..1023 (stride 1280)
    mm_k<32, AM_PLAIN, OM_BF16><<<dim3(64), blk, 0, stream>>>(
        wp1, wot, nullptr, wfin, nullptr, nullptr, 1024, 1280, nullptr, nullptr, nullptr);

    // sparse masked attention
    attn_k<<<dim3(B_ * L_), blk, 0, stream>>>(k_bf, v_bf, semsyn, to_sem, q_bf, ctx_bf);

    // final: [ctx | temb[tstype]] @ wfin^T + beff -> out1, out2 rows 1..L ; blocks 512.. do root
    mm_k<40, AM_CONCAT, OM_FINAL><<<dim3(576), blk, 0, stream>>>(
        ctx_bf, wfin, beff, nullptr, out1, out2, KP_, 1024, tstype, te_bf, broot);
}